// Round 11
// baseline (87.624 us; speedup 1.0000x reference)
//
#include <hip/hip_runtime.h>
#include <stdint.h>

#define IN_F   4096
#define OUT_F  11008
#define BATCH  8
#define RPW    2              // output rows per wave (1 wave per block)
#define CHUNK  256            // i-values per chunk (64 lanes * 4 ints per DMA)
#define NCHUNK (IN_F/CHUNK)   // 16

typedef __attribute__((address_space(1))) const uint32_t* gas_t;
typedef __attribute__((address_space(3))) uint32_t* las_t;

// async global->LDS DMA, 16 B/lane: no VGPR destination, regalloc-proof
#define DMA16(gsrc, ldst) \
    __builtin_amdgcn_global_load_lds((gas_t)(gsrc), (las_t)(ldst), 16, 0, 0)

#define VWAIT(N)                                                             \
    do {                                                                     \
        asm volatile("s_waitcnt vmcnt(" #N ")" ::: "memory");                \
        __builtin_amdgcn_sched_barrier(0);                                   \
    } while (0)
#define SBAR() __builtin_amdgcn_sched_barrier(0)

__device__ __forceinline__ float qins_decode(int code, int sgn, float d0, float d1) {
    // |w| = exp2(d0 + code*d1); sign bit straight from the int32 sign (+1 / -1)
    const float e = __builtin_amdgcn_exp2f(fmaf((float)code, d1, d0));
    const uint32_t m = ((uint32_t)sgn) & 0x80000000u;
    return __uint_as_float(__float_as_uint(e) ^ m);
}

// issue one chunk's 4 weight DMAs into slot T (2 stored rows + 2 sign rows)
#define ISSUE(T, K)                                                          \
    do {                                                                     \
        const int _ip = (K) * CHUNK + il;                                    \
        _Pragma("unroll")                                                    \
        for (int r = 0; r < RPW; ++r)                                        \
            DMA16(stored + (o0 + r) * IN_F + _ip, &lds[T][r][0]);            \
        _Pragma("unroll")                                                    \
        for (int r = 0; r < RPW; ++r)                                        \
            DMA16(sign + (o0 + r) * IN_F + _ip, &lds[T][RPW + r][0]);        \
    } while (0)

// consume slot T for chunk K: weights from LDS, x straight from global (L1-hot)
#define COMPUTE(T, K)                                                        \
    do {                                                                     \
        int4 c[RPW], g[RPW];                                                 \
        _Pragma("unroll")                                                    \
        for (int r = 0; r < RPW; ++r) {                                      \
            c[r] = *reinterpret_cast<const int4*>(&lds[T][r][il]);           \
            g[r] = *reinterpret_cast<const int4*>(&lds[T][RPW + r][il]);     \
        }                                                                    \
        float w[RPW][4];                                                     \
        _Pragma("unroll")                                                    \
        for (int r = 0; r < RPW; ++r) {                                      \
            w[r][0] = qins_decode(c[r].x, g[r].x, d0, d1);                   \
            w[r][1] = qins_decode(c[r].y, g[r].y, d0, d1);                   \
            w[r][2] = qins_decode(c[r].z, g[r].z, d0, d1);                   \
            w[r][3] = qins_decode(c[r].w, g[r].w, d0, d1);                   \
        }                                                                    \
        _Pragma("unroll")                                                    \
        for (int b = 0; b < BATCH; ++b) {                                    \
            const float4 t = *reinterpret_cast<const float4*>(               \
                x + b * IN_F + (K) * CHUNK + il);                            \
            _Pragma("unroll")                                                \
            for (int r = 0; r < RPW; ++r) {                                  \
                float a = acc[r][b];                                         \
                a = fmaf(w[r][0], t.x, a);                                   \
                a = fmaf(w[r][1], t.y, a);                                   \
                a = fmaf(w[r][2], t.z, a);                                   \
                a = fmaf(w[r][3], t.w, a);                                   \
                acc[r][b] = a;                                               \
            }                                                                \
        }                                                                    \
    } while (0)

__global__ __launch_bounds__(64)
void qins_linear_kernel(const float* __restrict__ x,
                        const uint32_t* __restrict__ stored,
                        const uint32_t* __restrict__ sign,
                        const float* __restrict__ log_min,
                        const float* __restrict__ log_max,
                        const float* __restrict__ bias,
                        float* __restrict__ out)
{
    // [slot][stream][ints]: 2 x 4 x 1 KB = 8 KB -> LDS allows ~20 blocks/CU
    __shared__ int lds[2][2 * RPW][CHUNK];

    const int lane = threadIdx.x;          // 64 threads = 1 wave
    const int o0   = blockIdx.x * RPW;
    const int il   = lane * 4;             // int index of this lane's 16 B

    const float lmin = log_min[0];
    const float lmax = log_max[0];
    const float L2E  = 1.44269504088896340736f;
    // log2(|w|) = d0 + code*d1
    const float d1 = -(lmax - lmin) * (L2E / 254.0f);
    const float d0 = (lmin + (lmax - lmin) * (255.0f / 254.0f)) * L2E;

    float acc[RPW][BATCH];
#pragma unroll
    for (int r = 0; r < RPW; ++r)
#pragma unroll
        for (int b = 0; b < BATCH; ++b) acc[r][b] = 0.0f;

    // prologue: chunks 0 and 1 in flight (8 outstanding DMAs)
    ISSUE(0, 0);
    ISSUE(1, 1);
    SBAR();

#pragma unroll 1
    for (int k = 0; k < NCHUNK - 2; k += 2) {
        VWAIT(4);                  // chunk k ready; chunk k+1's 4 stay in flight
        COMPUTE(0, k);
        SBAR();
        ISSUE(0, k + 2);           // refill slot 0 -> chunk k+2
        SBAR();
        VWAIT(4);                  // chunk k+1 ready
        COMPUTE(1, k + 1);
        SBAR();
        ISSUE(1, k + 3);           // refill slot 1 -> chunk k+3
        SBAR();
    }
    VWAIT(4);
    COMPUTE(0, NCHUNK - 2);        // chunk 14
    VWAIT(0);
    COMPUTE(1, NCHUNK - 1);        // chunk 15

    // full-wave butterfly reduction for the 16 (row,batch) partials
#pragma unroll
    for (int r = 0; r < RPW; ++r)
#pragma unroll
        for (int b = 0; b < BATCH; ++b) {
            float v = acc[r][b];
#pragma unroll
            for (int s = 32; s >= 1; s >>= 1)
                v += __shfl_xor(v, s, 64);
            acc[r][b] = v;
        }

    if (lane == 0) {
#pragma unroll
        for (int r = 0; r < RPW; ++r) {
            const float bv = bias[o0 + r];
#pragma unroll
            for (int b = 0; b < BATCH; ++b)
                out[(size_t)b * OUT_F + o0 + r] = acc[r][b] + bv;
        }
    }
}

extern "C" void kernel_launch(void* const* d_in, const int* in_sizes, int n_in,
                              void* d_out, int out_size, void* d_ws, size_t ws_size,
                              hipStream_t stream)
{
    const float*    x      = (const float*)d_in[0];
    const uint32_t* stored = (const uint32_t*)d_in[1];
    const uint32_t* sign   = (const uint32_t*)d_in[2];
    const float*    lmin   = (const float*)d_in[3];
    const float*    lmax   = (const float*)d_in[4];
    const float*    bias   = (const float*)d_in[5];
    float* out = (float*)d_out;

    dim3 grid(OUT_F / RPW), block(64);
    qins_linear_kernel<<<grid, block, 0, stream>>>(x, stored, sign, lmin, lmax, bias, out);
}

// Round 12
// 72.828 us; speedup vs baseline: 1.2032x; 1.2032x over previous
//
#include <hip/hip_runtime.h>
#include <stdint.h>

#define IN_F   4096
#define OUT_F  11008
#define BATCH  8
#define WAVES  4
#define RPW    2                  // rows per wave
#define RPB    (WAVES*RPW)        // 8 rows per block
#define CHUNK  128                // i-values per chunk
#define NCHUNK (IN_F/CHUNK)       // 32
#define SLOTI  (3*RPB*CHUNK)      // ints per LDS slot: 3072 (stored+sign+x)

typedef __attribute__((address_space(1))) const uint32_t* gas_t;
typedef __attribute__((address_space(3))) uint32_t* las_t;

// async global->LDS DMA, 16 B/lane: per-lane GLOBAL address, wave-uniform
// LDS base (+lane*16 implicit). No VGPR destination -> regalloc-proof.
#define DMA16(gsrc, ldst) \
    __builtin_amdgcn_global_load_lds((gas_t)(gsrc), (las_t)(ldst), 16, 0, 0)

__device__ __forceinline__ float qins_decode(int code, int sgn, float d0, float d1) {
    // |w| = exp2(d0 + code*d1); sign bit straight from the int32 sign (+1 / -1)
    const float e = __builtin_amdgcn_exp2f(fmaf((float)code, d1, d0));
    const uint32_t m = ((uint32_t)sgn) & 0x80000000u;
    return __uint_as_float(__float_as_uint(e) ^ m);
}

__global__ __launch_bounds__(256, 4)
void qins_linear_kernel(const float* __restrict__ x,
                        const uint32_t* __restrict__ stored,
                        const uint32_t* __restrict__ sign,
                        const float* __restrict__ log_min,
                        const float* __restrict__ log_max,
                        const float* __restrict__ bias,
                        float* __restrict__ out)
{
    // slot layout (ints): [0,1024) stored 8x128 | [1024,2048) sign | [2048,3072) x 8x128
    // segment s (1 KB) inside each region holds rows 2s,2s+1 (row-major 128 each)
    __shared__ int lds[2][SLOTI];

    const int tid  = threadIdx.x;
    const int lane = tid & 63;
    const int wave = tid >> 6;
    const int o0   = blockIdx.x * RPB;

    const float lmin = log_min[0];
    const float lmax = log_max[0];
    const float L2E  = 1.44269504088896340736f;
    // log2(|w|) = d0 + code*d1
    const float d1 = -(lmax - lmin) * (L2E / 254.0f);
    const float d0 = (lmin + (lmax - lmin) * (255.0f / 254.0f)) * L2E;

    // DMA source addressing: this wave stages segment `wave` of each region.
    // lanes 0-31 cover row 2w (ints 0..127), lanes 32-63 cover row 2w+1.
    const int sub = lane >> 5;
    const int i32 = (lane & 31) * 4;
    const uint32_t* gs = stored + (size_t)(o0 + 2 * wave + sub) * IN_F + i32;
    const uint32_t* gg = sign   + (size_t)(o0 + 2 * wave + sub) * IN_F + i32;
    const uint32_t* gx = (const uint32_t*)x + (size_t)(2 * wave + sub) * IN_F + i32;

    float acc[RPW][BATCH];
#pragma unroll
    for (int r = 0; r < RPW; ++r)
#pragma unroll
        for (int b = 0; b < BATCH; ++b) acc[r][b] = 0.0f;

    // prologue: stage chunk 0 into slot 0 (12 DMAs block-wide, 3 per wave)
    {
        DMA16(gs, &lds[0][wave * 256]);
        DMA16(gg, &lds[0][1024 + wave * 256]);
        DMA16(gx, &lds[0][2048 + wave * 256]);
    }
    __syncthreads();   // compiler emits vmcnt(0) before s_barrier -> chunk 0 ready

#pragma unroll 1
    for (int k = 0; k < NCHUNK; ++k) {
        const int cur = k & 1;
        // stage chunk k+1 into the other slot (its loads stay in flight
        // during compute; drained at the barrier below)
        if (k + 1 < NCHUNK) {
            const int nxt = cur ^ 1;
            const int ip  = (k + 1) * CHUNK;
            DMA16(gs + ip, &lds[nxt][wave * 256]);
            DMA16(gg + ip, &lds[nxt][1024 + wave * 256]);
            DMA16(gx + ip, &lds[nxt][2048 + wave * 256]);
        }

        // compute chunk k from LDS: rows 2w,2w+1; lane covers i = 2*lane,2*lane+1
        {
            const int li = lane * 2;
            const int2 c0 = *reinterpret_cast<const int2*>(&lds[cur][wave * 256 + li]);
            const int2 c1 = *reinterpret_cast<const int2*>(&lds[cur][wave * 256 + 128 + li]);
            const int2 g0 = *reinterpret_cast<const int2*>(&lds[cur][1024 + wave * 256 + li]);
            const int2 g1 = *reinterpret_cast<const int2*>(&lds[cur][1024 + wave * 256 + 128 + li]);
            const float w00 = qins_decode(c0.x, g0.x, d0, d1);
            const float w01 = qins_decode(c0.y, g0.y, d0, d1);
            const float w10 = qins_decode(c1.x, g1.x, d0, d1);
            const float w11 = qins_decode(c1.y, g1.y, d0, d1);
#pragma unroll
            for (int b = 0; b < BATCH; ++b) {
                const float2 xv = *reinterpret_cast<const float2*>(
                    &lds[cur][2048 + (b >> 1) * 256 + (b & 1) * 128 + li]);
                acc[0][b] = fmaf(w01, xv.y, fmaf(w00, xv.x, acc[0][b]));
                acc[1][b] = fmaf(w11, xv.y, fmaf(w10, xv.x, acc[1][b]));
            }
        }
        __syncthreads();   // drains next chunk's DMAs + release both slots
    }

    // butterfly reduction of the 16 (row,batch) partials across the wave
#pragma unroll
    for (int r = 0; r < RPW; ++r)
#pragma unroll
        for (int b = 0; b < BATCH; ++b) {
            float v = acc[r][b];
#pragma unroll
            for (int s = 32; s >= 1; s >>= 1)
                v += __shfl_xor(v, s, 64);
            acc[r][b] = v;
        }

    if (lane == 0) {
#pragma unroll
        for (int r = 0; r < RPW; ++r) {
            const int row = o0 + 2 * wave + r;
            const float bv = bias[row];
#pragma unroll
            for (int b = 0; b < BATCH; ++b)
                out[(size_t)b * OUT_F + row] = acc[r][b] + bv;
        }
    }
}

extern "C" void kernel_launch(void* const* d_in, const int* in_sizes, int n_in,
                              void* d_out, int out_size, void* d_ws, size_t ws_size,
                              hipStream_t stream)
{
    const float*    x      = (const float*)d_in[0];
    const uint32_t* stored = (const uint32_t*)d_in[1];
    const uint32_t* sign   = (const uint32_t*)d_in[2];
    const float*    lmin   = (const float*)d_in[3];
    const float*    lmax   = (const float*)d_in[4];
    const float*    bias   = (const float*)d_in[5];
    float* out = (float*)d_out;

    dim3 grid(OUT_F / RPB), block(WAVES * 64);
    qins_linear_kernel<<<grid, block, 0, stream>>>(x, stored, sign, lmin, lmax, bias, out);
}